// Round 7
// baseline (251.901 us; speedup 1.0000x reference)
//
#include <hip/hip_runtime.h>
#include <cstdint>

typedef unsigned short u16;
typedef __bf16 bf16x8 __attribute__((ext_vector_type(8)));
typedef float f32x4 __attribute__((ext_vector_type(4)));

#define T_SEQ  2048
#define D_DIM  1024
#define H_DIM  512
#define E_NUM  8
#define M_TOK  2048
#define BT_TOK 4096
#define MAXP   3072   // M + per-expert 128-pad worst case (2048 + 8*127 <= 3072)
#define NSPLIT_NONE (1 << 28)

static __device__ __forceinline__ u16 f2bf(float f) {
    union { float f; uint32_t u; } v; v.f = f;
    uint32_t u = v.u;
    return (u16)((u + 0x7FFFu + ((u >> 16) & 1u)) >> 16);  // RNE
}
static __device__ __forceinline__ uint32_t pack2(float a, float b) {
    return (uint32_t)f2bf(a) | ((uint32_t)f2bf(b) << 16);
}

// async global -> LDS, 16B per lane. lptr must be the wave-uniform base;
// HW scatters lane i to lptr + i*16 (m104/m108).
static __device__ __forceinline__ void gl_lds16(const u16* g, u16* l) {
    __builtin_amdgcn_global_load_lds(
        (const __attribute__((address_space(1))) uint32_t*)g,
        (__attribute__((address_space(3))) uint32_t*)l, 16, 0, 0);
}

// bounded expert search: last e with base[e] <= m  (base monotone, m < base[E_NUM])
static __device__ __forceinline__ int find_expert(int m, const int* __restrict__ base) {
    int e = 0;
    #pragma unroll
    for (int ee = 0; ee < E_NUM - 1; ++ee)
        if (m >= base[ee + 1]) e = ee + 1;
    return e;
}

// one cvt unit: float4 -> 4x bf16 (8B)
static __device__ __forceinline__ void cvt4(const float* __restrict__ s,
                                            u16* __restrict__ d, long off) {
    float4 v = ((const float4*)s)[off];
    uint2 o;
    o.x = pack2(v.x, v.y);
    o.y = pack2(v.z, v.w);
    ((uint2*)d)[off] = o;
}

// ---------------- device bodies ----------------

// gating: fp32 float4 dots, sigmoid, argmax, 2-way softmax. One block per token.
__device__ __forceinline__ void gating_body(
    int m,
    const float* __restrict__ x,
    const int* __restrict__ ib, const int* __restrict__ itx,
    const float* __restrict__ sgw, const float* __restrict__ sgb,
    const float* __restrict__ egw, const float* __restrict__ egb,
    const float* __restrict__ ebias,
    float* __restrict__ shw, float* __restrict__ expw,
    int* __restrict__ top1, int* __restrict__ rowidx,
    float* xs, float* sc)
{
    int tid = threadIdx.x;
    int row = ib[m] * T_SEQ + itx[m];
    if (tid == 0) rowidx[m] = row;
    const float* xr = x + (size_t)row * D_DIM;
    ((float4*)xs)[tid] = ((const float4*)xr)[tid];
    __syncthreads();
    int lane = tid & 63, w4 = tid >> 6;
    for (int sidx = w4; sidx < 9; sidx += 4) {
        const float* wr = (sidx == 0) ? sgw : (egw + (size_t)(sidx - 1) * D_DIM);
        float acc = 0.f;
        #pragma unroll
        for (int i = 0; i < 4; ++i) {        // 4x float4 per lane, 256 f4 total
            int idx = i * 64 + lane;
            float4 xv = ((const float4*)xs)[idx];
            float4 wv = ((const float4*)wr)[idx];
            acc += xv.x * wv.x + xv.y * wv.y + xv.z * wv.z + xv.w * wv.w;
        }
        #pragma unroll
        for (int o = 32; o > 0; o >>= 1) acc += __shfl_xor(acc, o);
        if (lane == 0) sc[sidx] = acc;
    }
    __syncthreads();
    if (tid == 0) {
        float ss = 1.f / (1.f + expf(-(sc[0] + sgb[0])));
        float es[E_NUM];
        float best = -1e30f; int bi = 0;
        #pragma unroll
        for (int e = 0; e < E_NUM; ++e) {
            es[e] = 1.f / (1.f + expf(-(sc[1 + e] + egb[e])));
            float t = es[e] + ebias[e];
            if (t > best) { best = t; bi = e; }   // strict > == jnp.argmax first-max
        }
        float ts = es[bi];
        shw[m]  = 1.f / (1.f + expf(ts - ss));
        expw[m] = 1.f / (1.f + expf(ss - ts));
        top1[m] = bi;
    }
}

// bucket tokens by expert, 128-aligned bases (tile = 128 rows). Single block.
__device__ __forceinline__ void bucket_body(
    const int* __restrict__ top1,
    int* __restrict__ base, int* __restrict__ cnt, int* __restrict__ perm,
    int* sm)
{
    int* lc  = sm;                  // 8
    int* lb  = sm + E_NUM;          // 9
    int* cur = sm + 2 * E_NUM + 1;  // 8
    int tid = threadIdx.x;
    if (tid < E_NUM) { lc[tid] = 0; cur[tid] = 0; }
    __syncthreads();
    for (int m = tid; m < M_TOK; m += 256) atomicAdd(&lc[top1[m]], 1);
    __syncthreads();
    if (tid == 0) {
        int bacc = 0;
        for (int e = 0; e < E_NUM; ++e) { lb[e] = bacc; bacc += (lc[e] + 127) & ~127; }
        lb[E_NUM] = bacc;
    }
    __syncthreads();
    for (int m = tid; m < M_TOK; m += 256) {
        int e = top1[m];
        int pos = lb[e] + atomicAdd(&cur[e], 1);
        perm[pos] = m;
    }
    if (tid <= E_NUM) base[tid] = lb[tid];
    if (tid < E_NUM)  cnt[tid]  = lc[tid];
}

// silu-gate + LayerNorm, fp32 in -> bf16 out. One block per row.
template<bool SEL>
__device__ __forceinline__ void ln_body(
    int m,
    const float* __restrict__ X,
    const float* __restrict__ g, const float* __restrict__ b,
    u16* __restrict__ out,
    const int* __restrict__ base, const int* __restrict__ cnt,
    float* red)
{
    int tid = threadIdx.x;
    if (SEL) {
        bool valid = false;
        int tot = base[E_NUM];
        if (m < tot) {
            int e = find_expert(m, base);
            valid = (m - base[e]) < cnt[e];
        }
        if (!valid) {  // zero padding rows so E2's A-tiles are clean
            out[(size_t)m * H_DIM + tid] = 0;
            out[(size_t)m * H_DIM + tid + 256] = 0;
            return;
        }
    }
    const float* row = X + (size_t)m * D_DIM;   // [0:512]=x1, [512:1024]=x2
    float a0 = row[tid],       c0 = row[H_DIM + tid];
    float a1 = row[tid + 256], c1 = row[H_DIM + tid + 256];
    float v0 = (a0 / (1.f + expf(-a0))) * c0;
    float v1 = (a1 / (1.f + expf(-a1))) * c1;
    float s = v0 + v1, s2 = v0 * v0 + v1 * v1;
    #pragma unroll
    for (int o = 32; o > 0; o >>= 1) {
        s  += __shfl_xor(s, o);
        s2 += __shfl_xor(s2, o);
    }
    int w = tid >> 6;
    if ((tid & 63) == 0) { red[w] = s; red[4 + w] = s2; }
    __syncthreads();
    s  = red[0] + red[1] + red[2] + red[3];
    s2 = red[4] + red[5] + red[6] + red[7];
    float mu  = s * (1.f / H_DIM);
    float var = s2 * (1.f / H_DIM) - mu * mu;
    float inv = rsqrtf(var + 1e-5f);
    out[(size_t)m * H_DIM + tid]       = f2bf((v0 - mu) * inv * g[tid] + b[tid]);
    out[(size_t)m * H_DIM + tid + 256] = f2bf((v1 - mu) * inv * g[tid + 256] + b[tid + 256]);
}

// MFMA GEMM: 128x128 tile, BK=64, DOUBLE-BUFFERED 2x32KB LDS (round-6 verified).
// Per K-step: issue next tile's global_load_lds FIRST, then 32 MFMA on current
// buffer, then one __syncthreads (vmcnt drain lands after compute -> DMA hidden).
template<int MODE, int KLEN>
__device__ __forceinline__ void gemm_body(
    int bn, int bm,
    const u16* __restrict__ A, int lda,
    const u16* __restrict__ W0, const u16* __restrict__ W1, int nsplit,
    const float* __restrict__ b0, const float* __restrict__ b1,
    float* __restrict__ C,
    const int* __restrict__ base, const int* __restrict__ cnt,
    const int* __restrict__ perm, const int* __restrict__ rowidx,
    const float* __restrict__ shw, const float* __restrict__ expw,
    u16* lds)   // 2 x 32 KB: per buffer A[128][64] | B[128][64]
{
    constexpr int NITER = KLEN / 64;
    const int tid   = threadIdx.x;
    const int mbase = bm * 128;

    int pend = 0;
    if (MODE >= 2) {
        const int tot = base[E_NUM];
        if (mbase >= tot) return;          // block-uniform exits before any barrier
        int e = find_expert(mbase, base);  // 128-aligned: tile never spans experts
        pend = base[e] + cnt[e];
        if (mbase >= pend) return;         // all-pad tile: output never read
        const size_t wstride = (size_t)H_DIM * D_DIM;
        W0 += (size_t)e * wstride;
        if (MODE == 2) W1 += (size_t)e * wstride;
        b0 += e * ((MODE == 2) ? H_DIM : D_DIM);
        if (MODE == 2) b1 += e * H_DIM;
    }

    const int w  = tid >> 6;        // wave 0..3
    const int l  = tid & 63;
    const int sr = tid >> 3;        // staging row-in-round 0..31
    const int sc = tid & 7;         // staging 16B-chunk 0..7

    // K-invariant global row pointers, 4 rounds x 32 rows = 128 rows each side.
    // Physical LDS chunk p holds logical chunk p^(r&7).
    const u16* agp[4];
    #pragma unroll
    for (int t = 0; t < 4; ++t) {
        int r = t * 32 + sr;
        int grow;
        if (MODE == 2) {
            int p  = mbase + r;
            int pp = (p < pend) ? p : (pend - 1);   // clamp pad rows to a valid token
            grow = rowidx[perm[pp]];
        } else {
            grow = mbase + r;
        }
        agp[t] = A + (size_t)grow * lda + (sc ^ (r & 7)) * 8;
    }
    const u16* bgp[4];
    #pragma unroll
    for (int t = 0; t < 4; ++t) {
        int r = t * 32 + sr;
        int n = bn * 128 + r;
        bgp[t] = ((n < nsplit) ? (W0 + (size_t)n * KLEN)
                               : (W1 + (size_t)(n - nsplit) * KLEN)) + (sc ^ (r & 7)) * 8;
    }

    const int l16 = l & 15, quad = l >> 4;
    const int wm = w >> 1, wn = w & 1;

    // K-invariant LDS read byte-offsets within one buffer
    // (kx=1 is offset^64: chunk index flips bit 2)
    int avo[4], bvo[4];
    #pragma unroll
    for (int i = 0; i < 4; ++i) {
        int R = wm * 64 + i * 16 + l16;
        avo[i] = R * 128 + ((quad ^ (R & 7)) * 16);
    }
    #pragma unroll
    for (int j = 0; j < 4; ++j) {
        int R = wn * 64 + j * 16 + l16;
        bvo[j] = 16384 + R * 128 + ((quad ^ (R & 7)) * 16);
    }

    f32x4 acc[4][4];
    #pragma unroll
    for (int i = 0; i < 4; ++i)
        #pragma unroll
        for (int j = 0; j < 4; ++j)
            acc[i][j] = (f32x4){0.f, 0.f, 0.f, 0.f};

    const int kstart = (bm + bn * 3) & (NITER - 1);   // channel-spread rotation
    const char* ldsc = (const char*)lds;

    // prologue: stage tile 0 into buffer 0
    {
        int k0 = kstart * 64;
        #pragma unroll
        for (int t = 0; t < 4; ++t)
            gl_lds16(agp[t] + k0, lds + t * 2048 + w * 512);
        #pragma unroll
        for (int t = 0; t < 4; ++t)
            gl_lds16(bgp[t] + k0, lds + 8192 + t * 2048 + w * 512);
    }
    __syncthreads();

    for (int it = 0; it < NITER; ++it) {
        const int cur = it & 1;
        if (it + 1 < NITER) {               // issue next tile's DMA before compute
            int k0 = ((it + 1 + kstart) & (NITER - 1)) * 64;
            u16* lb = lds + (cur ^ 1) * 16384;
            #pragma unroll
            for (int t = 0; t < 4; ++t)
                gl_lds16(agp[t] + k0, lb + t * 2048 + w * 512);
            #pragma unroll
            for (int t = 0; t < 4; ++t)
                gl_lds16(bgp[t] + k0, lb + 8192 + t * 2048 + w * 512);
        }
        const char* lb = ldsc + cur * 32768;
        #pragma unroll
        for (int kx = 0; kx < 2; ++kx) {
            bf16x8 av[4], bv[4];
            #pragma unroll
            for (int i = 0; i < 4; ++i)
                av[i] = *(const bf16x8*)(lb + (avo[i] ^ (kx * 64)));
            #pragma unroll
            for (int j = 0; j < 4; ++j)
                bv[j] = *(const bf16x8*)(lb + (bvo[j] ^ (kx * 64)));
            #pragma unroll
            for (int i = 0; i < 4; ++i)
                #pragma unroll
                for (int j = 0; j < 4; ++j)
                    acc[i][j] = __builtin_amdgcn_mfma_f32_16x16x32_bf16(av[i], bv[j], acc[i][j], 0, 0, 0);
        }
        if (it + 1 < NITER) __syncthreads();   // drains vmcnt AFTER compute: DMA hidden
    }

    if (MODE == 3) {
        #pragma unroll
        for (int i = 0; i < 4; ++i) {
            #pragma unroll
            for (int rr = 0; rr < 4; ++rr) {
                int p = mbase + wm * 64 + i * 16 + quad * 4 + rr;
                if (p < pend) {
                    int tok = perm[p];
                    int row = rowidx[tok];
                    float sw = shw[tok], ew = expw[tok];
                    float* outr = C + (size_t)row * D_DIM;
                    #pragma unroll
                    for (int j = 0; j < 4; ++j) {
                        int gn = bn * 128 + wn * 64 + j * 16 + l16;
                        outr[gn] = outr[gn] * sw + (acc[i][j][rr] + b0[gn]) * ew;
                    }
                }
            }
        }
    } else {
        #pragma unroll
        for (int i = 0; i < 4; ++i) {
            #pragma unroll
            for (int rr = 0; rr < 4; ++rr) {
                int gm = mbase + wm * 64 + i * 16 + quad * 4 + rr;
                float* outr = C + (size_t)gm * D_DIM;
                #pragma unroll
                for (int j = 0; j < 4; ++j) {
                    int gn = bn * 128 + wn * 64 + j * 16 + l16;
                    float bias = (gn < nsplit) ? b0[gn] : b1[gn - nsplit];
                    outr[gn] = acc[i][j][rr] + bias;
                }
            }
        }
    }
}

// ---------------- fused launches (5-stage pipeline) ----------------

// L1: cvt{x, sw1, sw2} (5120 blocks) || gating (2048 blocks).
// Only G1's inputs convert here; the heavy expert-weight cvt moves to L2.
__global__ __launch_bounds__(256)
void k_cvt1_gating(const float* __restrict__ x,
                   const float* __restrict__ sw1, const float* __restrict__ sw2,
                   u16* __restrict__ xb, u16* __restrict__ sw1b, u16* __restrict__ sw2b,
                   const int* __restrict__ ib, const int* __restrict__ itx,
                   const float* __restrict__ sgw, const float* __restrict__ sgb,
                   const float* __restrict__ egw, const float* __restrict__ egb,
                   const float* __restrict__ ebias,
                   float* __restrict__ shw, float* __restrict__ expw,
                   int* __restrict__ top1, int* __restrict__ rowidx)
{
    __shared__ __align__(16) float smem[D_DIM + 16];
    int bx = blockIdx.x;
    if (bx >= 5120) {
        gating_body(bx - 5120, x, ib, itx, sgw, sgb, egw, egb, ebias,
                    shw, expw, top1, rowidx, smem, smem + D_DIM);
        return;
    }
    long i = (long)bx * 256 + threadIdx.x;   // covers 1310720 exactly
    if      (i < 1048576) cvt4(x,   xb,   i);
    else if (i < 1179648) cvt4(sw1, sw1b, i - 1048576);
    else                  cvt4(sw2, sw2b, i - 1179648);
}

// L2: G1 (256) || bucket (1) || cvt{sw3, ew1, ew2, ew3} (12800).
// The weight stream overlaps G1's MFMA work instead of serializing before it.
__global__ __launch_bounds__(256)
void k_g1_bucket_cvt2(const u16* __restrict__ xb,
                      const u16* __restrict__ sw1b, const u16* __restrict__ sw2b,
                      const float* __restrict__ sb1, const float* __restrict__ sb2,
                      float* __restrict__ x12,
                      const int* __restrict__ top1,
                      int* __restrict__ basep, int* __restrict__ cntp, int* __restrict__ perm,
                      const float* __restrict__ sw3, const float* __restrict__ ew1,
                      const float* __restrict__ ew2, const float* __restrict__ ew3,
                      u16* __restrict__ sw3b, u16* __restrict__ ew1b,
                      u16* __restrict__ ew2b, u16* __restrict__ ew3b)
{
    __shared__ __align__(16) u16 lds[2 * (128 + 128) * 64];   // 64 KB
    int bx = blockIdx.x;
    if (bx < 256) {
        gemm_body<0, 1024>(bx & 7, bx >> 3, xb, D_DIM, sw1b, sw2b, H_DIM, sb1, sb2, x12,
                           nullptr, nullptr, nullptr, nullptr, nullptr, nullptr, lds);
        return;
    }
    if (bx == 256) {
        bucket_body(top1, basep, cntp, perm, (int*)lds);
        return;
    }
    long i = (long)(bx - 257) * 256 + threadIdx.x;   // covers 3276800 exactly
    if      (i <  131072) cvt4(sw3, sw3b, i);
    else if (i < 1179648) cvt4(ew1, ew1b, i - 131072);
    else if (i < 2228224) cvt4(ew2, ew2b, i - 1179648);
    else                  cvt4(ew3, ew3b, i - 2228224);
}

// L3: shared LN (4096) || E1 (192). E1 needs only xb + bucket; LN needs x12.
// h12 is its OWN buffer (no x12 alias) -> no intra-launch race.
__global__ __launch_bounds__(256)
void k_ln_e1(const float* __restrict__ x12,
             const float* __restrict__ g, const float* __restrict__ b,
             u16* __restrict__ shn,
             const u16* __restrict__ xb,
             const u16* __restrict__ ew1b, const u16* __restrict__ ew2b,
             const float* __restrict__ eb1, const float* __restrict__ eb2,
             float* __restrict__ h12,
             const int* __restrict__ basep, const int* __restrict__ cntp,
             const int* __restrict__ perm, const int* __restrict__ rowidx)
{
    __shared__ __align__(16) u16 lds[2 * (128 + 128) * 64];
    int bx = blockIdx.x;
    if (bx < BT_TOK) {
        ln_body<false>(bx, x12, g, b, shn, nullptr, nullptr, (float*)lds);
    } else {
        int b2 = bx - BT_TOK;
        gemm_body<2, 1024>(b2 & 7, b2 >> 3, xb, D_DIM, ew1b, ew2b, H_DIM, eb1, eb2, h12,
                           basep, cntp, perm, rowidx, nullptr, nullptr, lds);
    }
}

// L4: G2 (256) || expert LN (3072). z is its OWN buffer (no sh alias).
__global__ __launch_bounds__(256)
void k_g2_lnsel(const u16* __restrict__ shn, const u16* __restrict__ sw3b,
                const float* __restrict__ sb3, float* __restrict__ out,
                const float* __restrict__ h12,
                const float* __restrict__ selg, const float* __restrict__ selb,
                u16* __restrict__ z,
                const int* __restrict__ basep, const int* __restrict__ cntp)
{
    __shared__ __align__(16) u16 lds[2 * (128 + 128) * 64];
    int bx = blockIdx.x;
    if (bx < 256) {
        gemm_body<1, 512>(bx & 7, bx >> 3, shn, H_DIM, sw3b, sw3b, NSPLIT_NONE, sb3, sb3, out,
                          nullptr, nullptr, nullptr, nullptr, nullptr, nullptr, lds);
    } else {
        ln_body<true>(bx - 256, h12, selg, selb, z, basep, cntp, (float*)lds);
    }
}

// L5: E2 blend-scatter (192)
__global__ __launch_bounds__(256)
void k_e2(const u16* __restrict__ z, const u16* __restrict__ ew3b,
          const float* __restrict__ eb3, float* __restrict__ out,
          const int* __restrict__ basep, const int* __restrict__ cntp,
          const int* __restrict__ perm, const int* __restrict__ rowidx,
          const float* __restrict__ shw, const float* __restrict__ expw)
{
    __shared__ __align__(16) u16 lds[2 * (128 + 128) * 64];
    int bx = blockIdx.x;
    gemm_body<3, 512>(bx & 7, bx >> 3, z, H_DIM, ew3b, ew3b, NSPLIT_NONE, eb3, eb3, out,
                      basep, cntp, perm, rowidx, shw, expw, lds);
}

extern "C" void kernel_launch(void* const* d_in, const int* in_sizes, int n_in,
                              void* d_out, int out_size, void* d_ws, size_t ws_size,
                              hipStream_t stream) {
    const float* x        = (const float*)d_in[0];
    const int*   index_b  = (const int*)d_in[1];
    const int*   index_t  = (const int*)d_in[2];
    const float* sw1      = (const float*)d_in[3];
    const float* sb1      = (const float*)d_in[4];
    const float* sw2      = (const float*)d_in[5];
    const float* sb2      = (const float*)d_in[6];
    const float* sw3      = (const float*)d_in[7];
    const float* sb3      = (const float*)d_in[8];
    const float* s_ln_g   = (const float*)d_in[9];
    const float* s_ln_b   = (const float*)d_in[10];
    const float* sg_w     = (const float*)d_in[11];
    const float* sg_b     = (const float*)d_in[12];
    const float* eg_w     = (const float*)d_in[13];
    const float* eg_b     = (const float*)d_in[14];
    const float* exp_bias = (const float*)d_in[15];
    const float* ew1      = (const float*)d_in[16];
    const float* eb1      = (const float*)d_in[17];
    const float* ew2      = (const float*)d_in[18];
    const float* eb2      = (const float*)d_in[19];
    const float* ew3      = (const float*)d_in[20];
    const float* eb3      = (const float*)d_in[21];
    const float* sel_ln_g = (const float*)d_in[22];
    const float* sel_ln_b = (const float*)d_in[23];
    float* out = (float*)d_out;
    char*  ws  = (char*)d_ws;

    // ---- ws layout (bytes) — h12 and z de-aliased for intra-launch overlap ----
    u16*   xb   = (u16*)(ws + 0);              //  8 MB  x bf16
    u16*   sw1b = (u16*)(ws + 8388608);        //  1 MB
    u16*   sw2b = (u16*)(ws + 9437184);        //  1 MB
    u16*   sw3b = (u16*)(ws + 10485760);       //  1 MB
    u16*   ew1b = (u16*)(ws + 11534336);       //  8 MB
    u16*   ew2b = (u16*)(ws + 19922944);       //  8 MB
    u16*   ew3b = (u16*)(ws + 28311552);       //  8 MB
    float* x12  = (float*)(ws + 36700160);     // 16 MB fp32 [x1|x2]
    u16*   sh   = (u16*)(ws + 53477376);       //  4 MB bf16
    float* shw    = (float*)(ws + 57671680);   // scalars (~few KB)
    float* expw   = shw + M_TOK;
    int*   top1   = (int*)(expw + M_TOK);
    int*   rowidx = top1 + M_TOK;
    int*   perm   = rowidx + M_TOK;
    int*   basep  = perm + MAXP;
    int*   cntp   = basep + 16;
    float* h12  = (float*)(ws + 58720256);     // 12 MB fp32 (own buffer)
    u16*   z    = (u16*)(ws + 71303168);       //  3 MB bf16 (own buffer)
    // total ~74.3 MB; harness fill covers 256 MiB of ws

    // L1: cvt{x,sw1,sw2} (5120) || gating (2048)
    k_cvt1_gating<<<dim3(5120 + M_TOK), dim3(256), 0, stream>>>(
        x, sw1, sw2, xb, sw1b, sw2b,
        index_b, index_t, sg_w, sg_b, eg_w, eg_b, exp_bias,
        shw, expw, top1, rowidx);

    // L2: G1 (256) || bucket (1) || cvt{sw3,ew1,ew2,ew3} (12800)
    k_g1_bucket_cvt2<<<dim3(257 + 12800), dim3(256), 0, stream>>>(
        xb, sw1b, sw2b, sb1, sb2, x12, top1, basep, cntp, perm,
        sw3, ew1, ew2, ew3, sw3b, ew1b, ew2b, ew3b);

    // L3: shared LN (4096) || E1 (192)
    k_ln_e1<<<dim3(BT_TOK + 8 * (MAXP / 128)), dim3(256), 0, stream>>>(
        x12, s_ln_g, s_ln_b, sh,
        xb, ew1b, ew2b, eb1, eb2, h12,
        basep, cntp, perm, rowidx);

    // L4: G2 (256) || expert LN (3072)
    k_g2_lnsel<<<dim3(256 + MAXP), dim3(256), 0, stream>>>(
        sh, sw3b, sb3, out,
        h12, sel_ln_g, sel_ln_b, z, basep, cntp);

    // L5: E2 blend-scatter (192)
    k_e2<<<dim3(8 * (MAXP / 128)), dim3(256), 0, stream>>>(
        z, ew3b, eb3, out, basep, cntp, perm, rowidx, shw, expw);
}

// Round 8
// 226.709 us; speedup vs baseline: 1.1111x; 1.1111x over previous
//
#include <hip/hip_runtime.h>
#include <cstdint>

typedef unsigned short u16;
typedef __bf16 bf16x8 __attribute__((ext_vector_type(8)));
typedef float f32x4 __attribute__((ext_vector_type(4)));

#define T_SEQ  2048
#define D_DIM  1024
#define H_DIM  512
#define E_NUM  8
#define M_TOK  2048
#define BT_TOK 4096
#define MAXP   3072   // M + per-expert 128-pad worst case (2048 + 8*127 <= 3072)
#define NSPLIT_NONE (1 << 28)

static __device__ __forceinline__ u16 f2bf(float f) {
    union { float f; uint32_t u; } v; v.f = f;
    uint32_t u = v.u;
    return (u16)((u + 0x7FFFu + ((u >> 16) & 1u)) >> 16);  // RNE
}
static __device__ __forceinline__ uint32_t pack2(float a, float b) {
    return (uint32_t)f2bf(a) | ((uint32_t)f2bf(b) << 16);
}

// async global -> LDS, 16B per lane. lptr must be the wave-uniform base;
// HW scatters lane i to lptr + i*16 (m104/m108).
static __device__ __forceinline__ void gl_lds16(const u16* g, u16* l) {
    __builtin_amdgcn_global_load_lds(
        (const __attribute__((address_space(1))) uint32_t*)g,
        (__attribute__((address_space(3))) uint32_t*)l, 16, 0, 0);
}

// bounded expert search: last e with base[e] <= m  (base monotone, m < base[E_NUM])
static __device__ __forceinline__ int find_expert(int m, const int* __restrict__ base) {
    int e = 0;
    #pragma unroll
    for (int ee = 0; ee < E_NUM - 1; ++ee)
        if (m >= base[ee + 1]) e = ee + 1;
    return e;
}

// one cvt unit: 8 floats -> 8 bf16 (16B load x2, one 16B store)
static __device__ __forceinline__ void cvt8(const float* __restrict__ s,
                                            u16* __restrict__ d, long off) {
    float4 v0 = ((const float4*)s)[off * 2];
    float4 v1 = ((const float4*)s)[off * 2 + 1];
    uint4 o;
    o.x = pack2(v0.x, v0.y);
    o.y = pack2(v0.z, v0.w);
    o.z = pack2(v1.x, v1.y);
    o.w = pack2(v1.z, v1.w);
    ((uint4*)d)[off] = o;
}

// ---------------- device bodies ----------------

// gating: fp32 float4 dots, sigmoid, argmax, 2-way softmax. One block per token.
__device__ __forceinline__ void gating_body(
    int m,
    const float* __restrict__ x,
    const int* __restrict__ ib, const int* __restrict__ itx,
    const float* __restrict__ sgw, const float* __restrict__ sgb,
    const float* __restrict__ egw, const float* __restrict__ egb,
    const float* __restrict__ ebias,
    float* __restrict__ shw, float* __restrict__ expw,
    int* __restrict__ top1, int* __restrict__ rowidx,
    float* xs, float* sc)
{
    int tid = threadIdx.x;
    int row = ib[m] * T_SEQ + itx[m];
    if (tid == 0) rowidx[m] = row;
    const float* xr = x + (size_t)row * D_DIM;
    ((float4*)xs)[tid] = ((const float4*)xr)[tid];
    __syncthreads();
    int lane = tid & 63, w4 = tid >> 6;
    for (int sidx = w4; sidx < 9; sidx += 4) {
        const float* wr = (sidx == 0) ? sgw : (egw + (size_t)(sidx - 1) * D_DIM);
        float acc = 0.f;
        #pragma unroll
        for (int i = 0; i < 4; ++i) {        // 4x float4 per lane, 256 f4 total
            int idx = i * 64 + lane;
            float4 xv = ((const float4*)xs)[idx];
            float4 wv = ((const float4*)wr)[idx];
            acc += xv.x * wv.x + xv.y * wv.y + xv.z * wv.z + xv.w * wv.w;
        }
        #pragma unroll
        for (int o = 32; o > 0; o >>= 1) acc += __shfl_xor(acc, o);
        if (lane == 0) sc[sidx] = acc;
    }
    __syncthreads();
    if (tid == 0) {
        float ss = 1.f / (1.f + expf(-(sc[0] + sgb[0])));
        float es[E_NUM];
        float best = -1e30f; int bi = 0;
        #pragma unroll
        for (int e = 0; e < E_NUM; ++e) {
            es[e] = 1.f / (1.f + expf(-(sc[1 + e] + egb[e])));
            float t = es[e] + ebias[e];
            if (t > best) { best = t; bi = e; }   // strict > == jnp.argmax first-max
        }
        float ts = es[bi];
        shw[m]  = 1.f / (1.f + expf(ts - ss));
        expw[m] = 1.f / (1.f + expf(ss - ts));
        top1[m] = bi;
    }
}

// bucket tokens by expert, 128-aligned bases (tile = 128 rows). Single block.
__device__ __forceinline__ void bucket_body(
    const int* __restrict__ top1,
    int* __restrict__ base, int* __restrict__ cnt, int* __restrict__ perm,
    int* sm)
{
    int* lc  = sm;                  // 8
    int* lb  = sm + E_NUM;          // 9
    int* cur = sm + 2 * E_NUM + 1;  // 8
    int tid = threadIdx.x;
    if (tid < E_NUM) { lc[tid] = 0; cur[tid] = 0; }
    __syncthreads();
    for (int m = tid; m < M_TOK; m += 256) atomicAdd(&lc[top1[m]], 1);
    __syncthreads();
    if (tid == 0) {
        int bacc = 0;
        for (int e = 0; e < E_NUM; ++e) { lb[e] = bacc; bacc += (lc[e] + 127) & ~127; }
        lb[E_NUM] = bacc;
    }
    __syncthreads();
    for (int m = tid; m < M_TOK; m += 256) {
        int e = top1[m];
        int pos = lb[e] + atomicAdd(&cur[e], 1);
        perm[pos] = m;
    }
    if (tid <= E_NUM) base[tid] = lb[tid];
    if (tid < E_NUM)  cnt[tid]  = lc[tid];
}

// silu-gate + LayerNorm, fp32 in -> bf16 out. One block per row.
template<bool SEL>
__device__ __forceinline__ void ln_body(
    int m,
    const float* __restrict__ X,
    const float* __restrict__ g, const float* __restrict__ b,
    u16* __restrict__ out,
    const int* __restrict__ base, const int* __restrict__ cnt,
    float* red)
{
    int tid = threadIdx.x;
    if (SEL) {
        bool valid = false;
        int tot = base[E_NUM];
        if (m < tot) {
            int e = find_expert(m, base);
            valid = (m - base[e]) < cnt[e];
        }
        if (!valid) {  // zero padding rows so E2's A-tiles are clean
            out[(size_t)m * H_DIM + tid] = 0;
            out[(size_t)m * H_DIM + tid + 256] = 0;
            return;
        }
    }
    const float* row = X + (size_t)m * D_DIM;   // [0:512]=x1, [512:1024]=x2
    float a0 = row[tid],       c0 = row[H_DIM + tid];
    float a1 = row[tid + 256], c1 = row[H_DIM + tid + 256];
    float v0 = (a0 / (1.f + expf(-a0))) * c0;
    float v1 = (a1 / (1.f + expf(-a1))) * c1;
    float s = v0 + v1, s2 = v0 * v0 + v1 * v1;
    #pragma unroll
    for (int o = 32; o > 0; o >>= 1) {
        s  += __shfl_xor(s, o);
        s2 += __shfl_xor(s2, o);
    }
    int w = tid >> 6;
    if ((tid & 63) == 0) { red[w] = s; red[4 + w] = s2; }
    __syncthreads();
    s  = red[0] + red[1] + red[2] + red[3];
    s2 = red[4] + red[5] + red[6] + red[7];
    float mu  = s * (1.f / H_DIM);
    float var = s2 * (1.f / H_DIM) - mu * mu;
    float inv = rsqrtf(var + 1e-5f);
    out[(size_t)m * H_DIM + tid]       = f2bf((v0 - mu) * inv * g[tid] + b[tid]);
    out[(size_t)m * H_DIM + tid + 256] = f2bf((v1 - mu) * inv * g[tid + 256] + b[tid + 256]);
}

// MFMA GEMM: 128x128 tile, BK=64, DOUBLE-BUFFERED 2x32KB LDS (round-6 verified).
// Per K-step: issue next tile's global_load_lds FIRST, then 32 MFMA on current
// buffer, then one __syncthreads (vmcnt drain lands after compute -> DMA hidden).
template<int MODE, int KLEN>
__device__ __forceinline__ void gemm_body(
    int bn, int bm,
    const u16* __restrict__ A, int lda,
    const u16* __restrict__ W0, const u16* __restrict__ W1, int nsplit,
    const float* __restrict__ b0, const float* __restrict__ b1,
    float* __restrict__ C,
    const int* __restrict__ base, const int* __restrict__ cnt,
    const int* __restrict__ perm, const int* __restrict__ rowidx,
    const float* __restrict__ shw, const float* __restrict__ expw,
    u16* lds)   // 2 x 32 KB: per buffer A[128][64] | B[128][64]
{
    constexpr int NITER = KLEN / 64;
    const int tid   = threadIdx.x;
    const int mbase = bm * 128;

    int pend = 0;
    if (MODE >= 2) {
        const int tot = base[E_NUM];
        if (mbase >= tot) return;          // block-uniform exits before any barrier
        int e = find_expert(mbase, base);  // 128-aligned: tile never spans experts
        pend = base[e] + cnt[e];
        if (mbase >= pend) return;         // all-pad tile: output never read
        const size_t wstride = (size_t)H_DIM * D_DIM;
        W0 += (size_t)e * wstride;
        if (MODE == 2) W1 += (size_t)e * wstride;
        b0 += e * ((MODE == 2) ? H_DIM : D_DIM);
        if (MODE == 2) b1 += e * H_DIM;
    }

    const int w  = tid >> 6;        // wave 0..3
    const int l  = tid & 63;
    const int sr = tid >> 3;        // staging row-in-round 0..31
    const int sc = tid & 7;         // staging 16B-chunk 0..7

    // K-invariant global row pointers, 4 rounds x 32 rows = 128 rows each side.
    // Physical LDS chunk p holds logical chunk p^(r&7).
    const u16* agp[4];
    #pragma unroll
    for (int t = 0; t < 4; ++t) {
        int r = t * 32 + sr;
        int grow;
        if (MODE == 2) {
            int p  = mbase + r;
            int pp = (p < pend) ? p : (pend - 1);   // clamp pad rows to a valid token
            grow = rowidx[perm[pp]];
        } else {
            grow = mbase + r;
        }
        agp[t] = A + (size_t)grow * lda + (sc ^ (r & 7)) * 8;
    }
    const u16* bgp[4];
    #pragma unroll
    for (int t = 0; t < 4; ++t) {
        int r = t * 32 + sr;
        int n = bn * 128 + r;
        bgp[t] = ((n < nsplit) ? (W0 + (size_t)n * KLEN)
                               : (W1 + (size_t)(n - nsplit) * KLEN)) + (sc ^ (r & 7)) * 8;
    }

    const int l16 = l & 15, quad = l >> 4;
    const int wm = w >> 1, wn = w & 1;

    // K-invariant LDS read byte-offsets within one buffer
    // (kx=1 is offset^64: chunk index flips bit 2)
    int avo[4], bvo[4];
    #pragma unroll
    for (int i = 0; i < 4; ++i) {
        int R = wm * 64 + i * 16 + l16;
        avo[i] = R * 128 + ((quad ^ (R & 7)) * 16);
    }
    #pragma unroll
    for (int j = 0; j < 4; ++j) {
        int R = wn * 64 + j * 16 + l16;
        bvo[j] = 16384 + R * 128 + ((quad ^ (R & 7)) * 16);
    }

    f32x4 acc[4][4];
    #pragma unroll
    for (int i = 0; i < 4; ++i)
        #pragma unroll
        for (int j = 0; j < 4; ++j)
            acc[i][j] = (f32x4){0.f, 0.f, 0.f, 0.f};

    const int kstart = (bm + bn * 3) & (NITER - 1);   // channel-spread rotation
    const char* ldsc = (const char*)lds;

    // prologue: stage tile 0 into buffer 0
    {
        int k0 = kstart * 64;
        #pragma unroll
        for (int t = 0; t < 4; ++t)
            gl_lds16(agp[t] + k0, lds + t * 2048 + w * 512);
        #pragma unroll
        for (int t = 0; t < 4; ++t)
            gl_lds16(bgp[t] + k0, lds + 8192 + t * 2048 + w * 512);
    }
    __syncthreads();

    for (int it = 0; it < NITER; ++it) {
        const int cur = it & 1;
        if (it + 1 < NITER) {               // issue next tile's DMA before compute
            int k0 = ((it + 1 + kstart) & (NITER - 1)) * 64;
            u16* lb = lds + (cur ^ 1) * 16384;
            #pragma unroll
            for (int t = 0; t < 4; ++t)
                gl_lds16(agp[t] + k0, lb + t * 2048 + w * 512);
            #pragma unroll
            for (int t = 0; t < 4; ++t)
                gl_lds16(bgp[t] + k0, lb + 8192 + t * 2048 + w * 512);
        }
        const char* lb = ldsc + cur * 32768;
        #pragma unroll
        for (int kx = 0; kx < 2; ++kx) {
            bf16x8 av[4], bv[4];
            #pragma unroll
            for (int i = 0; i < 4; ++i)
                av[i] = *(const bf16x8*)(lb + (avo[i] ^ (kx * 64)));
            #pragma unroll
            for (int j = 0; j < 4; ++j)
                bv[j] = *(const bf16x8*)(lb + (bvo[j] ^ (kx * 64)));
            #pragma unroll
            for (int i = 0; i < 4; ++i)
                #pragma unroll
                for (int j = 0; j < 4; ++j)
                    acc[i][j] = __builtin_amdgcn_mfma_f32_16x16x32_bf16(av[i], bv[j], acc[i][j], 0, 0, 0);
        }
        if (it + 1 < NITER) __syncthreads();   // drains vmcnt AFTER compute: DMA hidden
    }

    if (MODE == 3) {
        #pragma unroll
        for (int i = 0; i < 4; ++i) {
            #pragma unroll
            for (int rr = 0; rr < 4; ++rr) {
                int p = mbase + wm * 64 + i * 16 + quad * 4 + rr;
                if (p < pend) {
                    int tok = perm[p];
                    int row = rowidx[tok];
                    float sw = shw[tok], ew = expw[tok];
                    float* outr = C + (size_t)row * D_DIM;
                    #pragma unroll
                    for (int j = 0; j < 4; ++j) {
                        int gn = bn * 128 + wn * 64 + j * 16 + l16;
                        outr[gn] = outr[gn] * sw + (acc[i][j][rr] + b0[gn]) * ew;
                    }
                }
            }
        }
    } else {
        #pragma unroll
        for (int i = 0; i < 4; ++i) {
            #pragma unroll
            for (int rr = 0; rr < 4; ++rr) {
                int gm = mbase + wm * 64 + i * 16 + quad * 4 + rr;
                float* outr = C + (size_t)gm * D_DIM;
                #pragma unroll
                for (int j = 0; j < 4; ++j) {
                    int gn = bn * 128 + wn * 64 + j * 16 + l16;
                    float bias = (gn < nsplit) ? b0[gn] : b1[gn - nsplit];
                    outr[gn] = acc[i][j][rr] + bias;
                }
            }
        }
    }
}

// ---------------- fused launches (6-stage pipeline, footprint-compatible fusions) ----------------

// L1: cvt{x,sw1,sw2} (2560 blocks, f8 units) || gating (2048). Both small-smem.
__global__ __launch_bounds__(256)
void k_cvt1_gating(const float* __restrict__ x,
                   const float* __restrict__ sw1, const float* __restrict__ sw2,
                   u16* __restrict__ xb, u16* __restrict__ sw1b, u16* __restrict__ sw2b,
                   const int* __restrict__ ib, const int* __restrict__ itx,
                   const float* __restrict__ sgw, const float* __restrict__ sgb,
                   const float* __restrict__ egw, const float* __restrict__ egb,
                   const float* __restrict__ ebias,
                   float* __restrict__ shw, float* __restrict__ expw,
                   int* __restrict__ top1, int* __restrict__ rowidx)
{
    __shared__ __align__(16) float smem[D_DIM + 16];
    int bx = blockIdx.x;
    if (bx >= 2560) {
        gating_body(bx - 2560, x, ib, itx, sgw, sgb, egw, egb, ebias,
                    shw, expw, top1, rowidx, smem, smem + D_DIM);
        return;
    }
    long i = (long)bx * 256 + threadIdx.x;   // covers 655360 f8-units exactly
    if      (i < 524288) cvt8(x,   xb,   i);
    else if (i < 589824) cvt8(sw1, sw1b, i - 524288);
    else                 cvt8(sw2, sw2b, i - 589824);
}

// L2: G1 (256) || bucket (1). GEMM-only kernel keeps its 64KB LDS to itself.
__global__ __launch_bounds__(256)
void k_g1_bucket(const u16* __restrict__ xb,
                 const u16* __restrict__ sw1b, const u16* __restrict__ sw2b,
                 const float* __restrict__ sb1, const float* __restrict__ sb2,
                 float* __restrict__ x12,
                 const int* __restrict__ top1,
                 int* __restrict__ basep, int* __restrict__ cntp, int* __restrict__ perm)
{
    __shared__ __align__(16) u16 lds[2 * (128 + 128) * 64];   // 64 KB
    int bx = blockIdx.x;
    if (bx < 256) {
        gemm_body<0, 1024>(bx & 7, bx >> 3, xb, D_DIM, sw1b, sw2b, H_DIM, sb1, sb2, x12,
                           nullptr, nullptr, nullptr, nullptr, nullptr, nullptr, lds);
    } else {
        bucket_body(top1, basep, cntp, perm, (int*)lds);
    }
}

// L3: shared LN (4096) || cvt{sw3,ew1,ew2} (4352). Both tiny-smem -> full occupancy.
__global__ __launch_bounds__(256)
void k_ln_cvt2(const float* __restrict__ x12,
               const float* __restrict__ g, const float* __restrict__ b,
               u16* __restrict__ shn,
               const float* __restrict__ sw3, const float* __restrict__ ew1,
               const float* __restrict__ ew2,
               u16* __restrict__ sw3b, u16* __restrict__ ew1b, u16* __restrict__ ew2b)
{
    __shared__ __align__(16) float smf[8];
    int bx = blockIdx.x;
    if (bx < BT_TOK) {
        ln_body<false>(bx, x12, g, b, shn, nullptr, nullptr, smf);
        return;
    }
    long i = (long)(bx - BT_TOK) * 256 + threadIdx.x;   // covers 1114112 f8-units exactly
    if      (i <  65536) cvt8(sw3, sw3b, i);
    else if (i < 589824) cvt8(ew1, ew1b, i - 65536);
    else                 cvt8(ew2, ew2b, i - 589824);
}

// L4: G2 (256) || E1 (192). GEMM + GEMM: compatible 64KB footprints.
__global__ __launch_bounds__(256)
void k_g2_e1(const u16* __restrict__ shn, const u16* __restrict__ sw3b,
             const float* __restrict__ sb3, float* __restrict__ out,
             const u16* __restrict__ xb,
             const u16* __restrict__ ew1b, const u16* __restrict__ ew2b,
             const float* __restrict__ eb1, const float* __restrict__ eb2,
             float* __restrict__ h12,
             const int* __restrict__ basep, const int* __restrict__ cntp,
             const int* __restrict__ perm, const int* __restrict__ rowidx)
{
    __shared__ __align__(16) u16 lds[2 * (128 + 128) * 64];
    int bx = blockIdx.x;
    if (bx < 256) {
        gemm_body<1, 512>(bx & 7, bx >> 3, shn, H_DIM, sw3b, sw3b, NSPLIT_NONE, sb3, sb3, out,
                          nullptr, nullptr, nullptr, nullptr, nullptr, nullptr, lds);
    } else {
        int b2 = bx - 256;
        gemm_body<2, 1024>(b2 & 7, b2 >> 3, xb, D_DIM, ew1b, ew2b, H_DIM, eb1, eb2, h12,
                           basep, cntp, perm, rowidx, nullptr, nullptr, lds);
    }
}

// L5: expert LN (3072) || cvt{ew3} (2048). ew3 only needed by E2 (L6).
__global__ __launch_bounds__(256)
void k_lnsel_cvt3(const float* __restrict__ h12,
                  const float* __restrict__ g, const float* __restrict__ b,
                  u16* __restrict__ z,
                  const int* __restrict__ basep, const int* __restrict__ cntp,
                  const float* __restrict__ ew3, u16* __restrict__ ew3b)
{
    __shared__ __align__(16) float smf[8];
    int bx = blockIdx.x;
    if (bx < MAXP) {
        ln_body<true>(bx, h12, g, b, z, basep, cntp, smf);
        return;
    }
    long i = (long)(bx - MAXP) * 256 + threadIdx.x;   // covers 524288 f8-units exactly
    cvt8(ew3, ew3b, i);
}

// L6: E2 blend-scatter (192)
__global__ __launch_bounds__(256)
void k_e2(const u16* __restrict__ z, const u16* __restrict__ ew3b,
          const float* __restrict__ eb3, float* __restrict__ out,
          const int* __restrict__ basep, const int* __restrict__ cntp,
          const int* __restrict__ perm, const int* __restrict__ rowidx,
          const float* __restrict__ shw, const float* __restrict__ expw)
{
    __shared__ __align__(16) u16 lds[2 * (128 + 128) * 64];
    int bx = blockIdx.x;
    gemm_body<3, 512>(bx & 7, bx >> 3, z, H_DIM, ew3b, ew3b, NSPLIT_NONE, eb3, eb3, out,
                      basep, cntp, perm, rowidx, shw, expw, lds);
}

extern "C" void kernel_launch(void* const* d_in, const int* in_sizes, int n_in,
                              void* d_out, int out_size, void* d_ws, size_t ws_size,
                              hipStream_t stream) {
    const float* x        = (const float*)d_in[0];
    const int*   index_b  = (const int*)d_in[1];
    const int*   index_t  = (const int*)d_in[2];
    const float* sw1      = (const float*)d_in[3];
    const float* sb1      = (const float*)d_in[4];
    const float* sw2      = (const float*)d_in[5];
    const float* sb2      = (const float*)d_in[6];
    const float* sw3      = (const float*)d_in[7];
    const float* sb3      = (const float*)d_in[8];
    const float* s_ln_g   = (const float*)d_in[9];
    const float* s_ln_b   = (const float*)d_in[10];
    const float* sg_w     = (const float*)d_in[11];
    const float* sg_b     = (const float*)d_in[12];
    const float* eg_w     = (const float*)d_in[13];
    const float* eg_b     = (const float*)d_in[14];
    const float* exp_bias = (const float*)d_in[15];
    const float* ew1      = (const float*)d_in[16];
    const float* eb1      = (const float*)d_in[17];
    const float* ew2      = (const float*)d_in[18];
    const float* eb2      = (const float*)d_in[19];
    const float* ew3      = (const float*)d_in[20];
    const float* eb3      = (const float*)d_in[21];
    const float* sel_ln_g = (const float*)d_in[22];
    const float* sel_ln_b = (const float*)d_in[23];
    float* out = (float*)d_out;
    char*  ws  = (char*)d_ws;

    // ---- ws layout (bytes) — h12/z de-aliased ----
    u16*   xb   = (u16*)(ws + 0);              //  8 MB  x bf16
    u16*   sw1b = (u16*)(ws + 8388608);        //  1 MB
    u16*   sw2b = (u16*)(ws + 9437184);        //  1 MB
    u16*   sw3b = (u16*)(ws + 10485760);       //  1 MB
    u16*   ew1b = (u16*)(ws + 11534336);       //  8 MB
    u16*   ew2b = (u16*)(ws + 19922944);       //  8 MB
    u16*   ew3b = (u16*)(ws + 28311552);       //  8 MB
    float* x12  = (float*)(ws + 36700160);     // 16 MB fp32 [x1|x2]
    u16*   sh   = (u16*)(ws + 53477376);       //  4 MB bf16
    float* shw    = (float*)(ws + 57671680);   // scalars
    float* expw   = shw + M_TOK;
    int*   top1   = (int*)(expw + M_TOK);
    int*   rowidx = top1 + M_TOK;
    int*   perm   = rowidx + M_TOK;
    int*   basep  = perm + MAXP;
    int*   cntp   = basep + 16;
    float* h12  = (float*)(ws + 58720256);     // 12 MB fp32 (own buffer)
    u16*   z    = (u16*)(ws + 71303168);       //  3 MB bf16 (own buffer)

    // L1: cvt{x,sw1,sw2} (2560) || gating (2048)
    k_cvt1_gating<<<dim3(2560 + M_TOK), dim3(256), 0, stream>>>(
        x, sw1, sw2, xb, sw1b, sw2b,
        index_b, index_t, sg_w, sg_b, eg_w, eg_b, exp_bias,
        shw, expw, top1, rowidx);

    // L2: G1 (256) || bucket (1)
    k_g1_bucket<<<dim3(257), dim3(256), 0, stream>>>(
        xb, sw1b, sw2b, sb1, sb2, x12, top1, basep, cntp, perm);

    // L3: shared LN (4096) || cvt{sw3,ew1,ew2} (4352)
    k_ln_cvt2<<<dim3(BT_TOK + 4352), dim3(256), 0, stream>>>(
        x12, s_ln_g, s_ln_b, sh,
        sw3, ew1, ew2, sw3b, ew1b, ew2b);

    // L4: G2 (256) || E1 (192)
    k_g2_e1<<<dim3(256 + 8 * (MAXP / 128)), dim3(256), 0, stream>>>(
        sh, sw3b, sb3, out,
        xb, ew1b, ew2b, eb1, eb2, h12,
        basep, cntp, perm, rowidx);

    // L5: expert LN (3072) || cvt{ew3} (2048)
    k_lnsel_cvt3<<<dim3(MAXP + 2048), dim3(256), 0, stream>>>(
        h12, sel_ln_g, sel_ln_b, z, basep, cntp, ew3, ew3b);

    // L6: E2 blend-scatter (192)
    k_e2<<<dim3(8 * (MAXP / 128)), dim3(256), 0, stream>>>(
        z, ew3b, eb3, out, basep, cntp, perm, rowidx, shw, expw);
}